// Round 1
// baseline (427.477 us; speedup 1.0000x reference)
//
#include <hip/hip_runtime.h>
#include <hip/hip_bf16.h>

#define T_TOK 8192
#define D_IN  4096
#define D_OUT 4096
#define NE    8
#define RR    8
#define SCALE 2.0f

__device__ __forceinline__ float bf2f(unsigned short u) {
    unsigned int i = ((unsigned int)u) << 16;
    float f; __builtin_memcpy(&f, &i, 4); return f;
}
__device__ __forceinline__ unsigned short f2bf(float f) {
    unsigned int x; __builtin_memcpy(&x, &f, 4);
    unsigned int r = (x + 0x7fffu + ((x >> 16) & 1u)) >> 16;
    return (unsigned short)r;
}

// ---------------- Wa f32 -> bf16 conversion (512 KB, trivial) ----------------
__global__ void conv_wa(const float* __restrict__ Wa, unsigned short* __restrict__ WaB) {
    int i4 = blockIdx.x * 256 + threadIdx.x;      // 65536 float4s = 262144 elems
    float4 v = ((const float4*)Wa)[i4];
    ushort4 u;
    u.x = f2bf(v.x); u.y = f2bf(v.y); u.z = f2bf(v.z); u.w = f2bf(v.w);
    ((ushort4*)WaB)[i4] = u;
}

// ---------------- Kernel 1: routing (a & b) + mid, one token per block -------
__global__ __launch_bounds__(256, 4)
void k1_mid(const float* __restrict__ x, const float* __restrict__ la,
            const float* __restrict__ lb, const unsigned short* __restrict__ WaB,
            float* __restrict__ mvec, int* __restrict__ fidx) {
    const int t  = blockIdx.x;
    const int tx = threadIdx.x;

    // --- routing A (all threads redundantly; broadcast loads) ---
    float l[8];
#pragma unroll
    for (int i = 0; i < 8; ++i) l[i] = la[t * 8 + i];
    int ea0 = 0; float b0 = l[0];
#pragma unroll
    for (int i = 1; i < 8; ++i) if (l[i] > b0) { b0 = l[i]; ea0 = i; }
    int ea1 = -1; float b1 = -1e30f;
#pragma unroll
    for (int i = 0; i < 8; ++i) if (i != ea0 && l[i] > b1) { b1 = l[i]; ea1 = i; }
    float wa1 = __expf(b1 - b0); float sa = 1.0f + wa1;
    float wa0 = 1.0f / sa; wa1 = wa1 / sa;

    // --- routing B ---
#pragma unroll
    for (int i = 0; i < 8; ++i) l[i] = lb[t * 8 + i];
    int f0 = 0; float c0 = l[0];
#pragma unroll
    for (int i = 1; i < 8; ++i) if (l[i] > c0) { c0 = l[i]; f0 = i; }
    int f1 = -1; float c1 = -1e30f;
#pragma unroll
    for (int i = 0; i < 8; ++i) if (i != f0 && l[i] > c1) { c1 = l[i]; f1 = i; }
    float wb1 = __expf(c1 - c0); float sb = 1.0f + wb1;
    float wb0 = 1.0f / sb; wb1 = wb1 / sb;

    // --- x fragment: 16 floats/thread as 4 coalesced float4 chunks ---
    const float4* xp = (const float4*)(x + (size_t)t * D_IN);
    float4 xf[4];
#pragma unroll
    for (int j = 0; j < 4; ++j) xf[j] = xp[j * 256 + tx];

    // --- 16 dot-partials: 2 experts x 8 r ---
    float vals[16];
#pragma unroll
    for (int slot = 0; slot < 2; ++slot) {
        int e = (slot == 0) ? ea0 : ea1;
        const ushort4* wp = (const ushort4*)(WaB + (size_t)e * RR * D_IN);
#pragma unroll
        for (int r = 0; r < 8; ++r) {
            float s = 0.f;
#pragma unroll
            for (int j = 0; j < 4; ++j) {
                ushort4 u = wp[r * 1024 + j * 256 + tx];
                float4 xv = xf[j];
                s += xv.x * bf2f(u.x) + xv.y * bf2f(u.y)
                   + xv.z * bf2f(u.z) + xv.w * bf2f(u.w);
            }
            vals[slot * 8 + r] = s;
        }
    }

    // --- reduce 16 values across 256 threads ---
    __shared__ float red[4][16];
    __shared__ float tot[16];
    const int lane = tx & 63, wid = tx >> 6;
#pragma unroll
    for (int v = 0; v < 16; ++v) {
        float s = vals[v];
#pragma unroll
        for (int off = 32; off > 0; off >>= 1) s += __shfl_down(s, off, 64);
        if (lane == 0) red[wid][v] = s;
    }
    __syncthreads();
    if (tx < 16) tot[tx] = red[0][tx] + red[1][tx] + red[2][tx] + red[3][tx];
    __syncthreads();
    if (tx < 8) {
        float mid = wa0 * tot[tx] + wa1 * tot[8 + tx];
        mvec[t * 16 + tx]     = SCALE * wb0 * mid;
        mvec[t * 16 + 8 + tx] = SCALE * wb1 * mid;
    }
    if (tx == 0) { fidx[2 * t] = f0; fidx[2 * t + 1] = f1; }
}

// ---------------- Kernel 2: out = m0 . Wb[f0,o,:] + m1 . Wb[f1,o,:] ----------
__device__ __forceinline__ float dot8(const float4& lo, const float4& hi,
                                      const float4& ma, const float4& mb) {
    return lo.x * ma.x + lo.y * ma.y + lo.z * ma.z + lo.w * ma.w
         + hi.x * mb.x + hi.y * mb.y + hi.z * mb.z + hi.w * mb.w;
}

__global__ __launch_bounds__(256, 2)
void k2_out(const float* __restrict__ Wb, const float* __restrict__ mvec,
            const int* __restrict__ fidx, float* __restrict__ out) {
    const int tx = threadIdx.x;
    const int o  = blockIdx.x * 256 + tx;
    const int t0 = blockIdx.y * 128;

    // all 8 experts' Wb row for this output column: 64 floats in regs
    float4 Wlo[8], Whi[8];
#pragma unroll
    for (int e = 0; e < 8; ++e) {
        const float4* wp = (const float4*)(Wb + ((size_t)e * D_OUT + o) * RR);
        Wlo[e] = wp[0]; Whi[e] = wp[1];
    }

#pragma unroll 2
    for (int t = t0; t < t0 + 128; ++t) {
        int e0 = fidx[2 * t], e1 = fidx[2 * t + 1];
        e0 = __builtin_amdgcn_readfirstlane(e0);
        e1 = __builtin_amdgcn_readfirstlane(e1);
        const float4* mp = (const float4*)(mvec + t * 16);
        float4 m0a = mp[0], m0b = mp[1], m1a = mp[2], m1b = mp[3];

        float acc;
        switch (e0) {
            case 0: acc = dot8(Wlo[0], Whi[0], m0a, m0b); break;
            case 1: acc = dot8(Wlo[1], Whi[1], m0a, m0b); break;
            case 2: acc = dot8(Wlo[2], Whi[2], m0a, m0b); break;
            case 3: acc = dot8(Wlo[3], Whi[3], m0a, m0b); break;
            case 4: acc = dot8(Wlo[4], Whi[4], m0a, m0b); break;
            case 5: acc = dot8(Wlo[5], Whi[5], m0a, m0b); break;
            case 6: acc = dot8(Wlo[6], Whi[6], m0a, m0b); break;
            default: acc = dot8(Wlo[7], Whi[7], m0a, m0b); break;
        }
        switch (e1) {
            case 0: acc += dot8(Wlo[0], Whi[0], m1a, m1b); break;
            case 1: acc += dot8(Wlo[1], Whi[1], m1a, m1b); break;
            case 2: acc += dot8(Wlo[2], Whi[2], m1a, m1b); break;
            case 3: acc += dot8(Wlo[3], Whi[3], m1a, m1b); break;
            case 4: acc += dot8(Wlo[4], Whi[4], m1a, m1b); break;
            case 5: acc += dot8(Wlo[5], Whi[5], m1a, m1b); break;
            case 6: acc += dot8(Wlo[6], Whi[6], m1a, m1b); break;
            default: acc += dot8(Wlo[7], Whi[7], m1a, m1b); break;
        }
        out[(size_t)t * D_OUT + o] = acc;
    }
}

// ---------------- aux losses: deterministic two-stage f64 reduction ----------
__global__ void aux_partial(const float* __restrict__ la, const float* __restrict__ lb,
                            double* __restrict__ part) {
    const int tx = threadIdx.x;
    const int t  = blockIdx.x * 256 + tx;
    double loc[16];
    {
        float l[8];
#pragma unroll
        for (int i = 0; i < 8; ++i) l[i] = la[t * 8 + i];
        float m = l[0];
#pragma unroll
        for (int i = 1; i < 8; ++i) m = fmaxf(m, l[i]);
        float s = 0.f; float e[8];
#pragma unroll
        for (int i = 0; i < 8; ++i) { e[i] = __expf(l[i] - m); s += e[i]; }
#pragma unroll
        for (int i = 0; i < 8; ++i) loc[i] = (double)(e[i] / s);
    }
    {
        float l[8];
#pragma unroll
        for (int i = 0; i < 8; ++i) l[i] = lb[t * 8 + i];
        float m = l[0];
#pragma unroll
        for (int i = 1; i < 8; ++i) m = fmaxf(m, l[i]);
        float s = 0.f; float e[8];
#pragma unroll
        for (int i = 0; i < 8; ++i) { e[i] = __expf(l[i] - m); s += e[i]; }
#pragma unroll
        for (int i = 0; i < 8; ++i) loc[8 + i] = (double)(e[i] / s);
    }
    __shared__ double red[4][16];
    const int lane = tx & 63, wid = tx >> 6;
#pragma unroll
    for (int v = 0; v < 16; ++v) {
        double s = loc[v];
#pragma unroll
        for (int off = 32; off > 0; off >>= 1) s += __shfl_down(s, off, 64);
        if (lane == 0) red[wid][v] = s;
    }
    __syncthreads();
    if (tx < 16)
        part[blockIdx.x * 16 + tx] = red[0][tx] + red[1][tx] + red[2][tx] + red[3][tx];
}

__global__ void aux_final(const double* __restrict__ part, float* __restrict__ out_aux) {
    const int tx = threadIdx.x;
    __shared__ double sl[16];
    if (tx < 16) {
        double s = 0.0;
#pragma unroll
        for (int b = 0; b < 32; ++b) s += part[b * 16 + tx];
        sl[tx] = s;
    }
    __syncthreads();
    if (tx == 0) {
        double pa[8], pb[8], ma = 0.0, mb = 0.0;
        for (int e = 0; e < 8; ++e) { pa[e] = sl[e] / 8192.0;     ma += pa[e] / 8.0; }
        for (int e = 0; e < 8; ++e) { pb[e] = sl[8 + e] / 8192.0; mb += pb[e] / 8.0; }
        double va = 0.0, vb = 0.0;
        for (int e = 0; e < 8; ++e) { double d = pa[e] - ma; va += d * d; }
        for (int e = 0; e < 8; ++e) { double d = pb[e] - mb; vb += d * d; }
        va /= 7.0; vb /= 7.0;
        out_aux[0] = (float)(8.0 * va);
        out_aux[1] = (float)(8.0 * vb);
    }
}

extern "C" void kernel_launch(void* const* d_in, const int* in_sizes, int n_in,
                              void* d_out, int out_size, void* d_ws, size_t ws_size,
                              hipStream_t stream) {
    const float* x  = (const float*)d_in[0];
    const float* la = (const float*)d_in[1];
    const float* lb = (const float*)d_in[2];
    const float* Wa = (const float*)d_in[3];
    const float* Wb = (const float*)d_in[4];
    float* out = (float*)d_out;

    // workspace layout
    char* ws = (char*)d_ws;
    unsigned short* WaB = (unsigned short*)ws;                   // 512 KB
    float* mvec = (float*)(ws + 524288);                         // 512 KB
    int*   fidx = (int*)(ws + 1048576);                          // 64 KB
    double* part = (double*)(ws + 1114112);                      // 4 KB

    conv_wa<<<256, 256, 0, stream>>>(Wa, WaB);
    aux_partial<<<32, 256, 0, stream>>>(la, lb, part);
    k1_mid<<<T_TOK, 256, 0, stream>>>(x, la, lb, WaB, mvec, fidx);
    k2_out<<<dim3(16, 64), 256, 0, stream>>>(Wb, mvec, fidx, out);
    aux_final<<<1, 64, 0, stream>>>(part, out + (size_t)T_TOK * D_OUT);
}